// Round 11
// baseline (449.886 us; speedup 1.0000x reference)
//
#include <hip/hip_runtime.h>
#include <math.h>

#define EMB 512
#define NM 5
#define HID 64
#define NQ 2048
#define NP 256
#define NRT 144               // row-tiles of 16
#define NC 16                 // K-chunks of 32 (K=512)
#define GRID 1024
#define XJOBS (NRT * NC)      // 2304 X wave-jobs
#define WJOBS 640             // 5m * 2half * 4ht * 16c
#define GEMM_BLKS 720
#define FUSED_BLKS 512

typedef __attribute__((ext_vector_type(8))) short short8;   // 8 bf16 = 4 VGPR
typedef __attribute__((ext_vector_type(4))) float floatx4;

// ws layout (bytes)
#define CTR_BY   0u                               // 2 counters (64B reserved)
#define A_BY     1024u                            // A[m][q][h] f32 (+b1)
#define B_BY     (A_BY + 2621440u)                // B[m][h/4][p][h%4] f32
#define PXH_BY   (B_BY + 327680u)                 // X-frag hi [rt*16+c][lane][8]
#define PWH_BY   (PXH_BY + 2359296u)              // W-frag hi [u][lane][8]
#define PWL_BY   (PWH_BY + 655360u)               // W-frag lo

__device__ inline unsigned short bfr(float f) {            // f32 -> bf16 RNE
    unsigned u = __float_as_uint(f);
    u += 0x7FFFu + ((u >> 16) & 1u);
    return (unsigned short)(u >> 16);
}

// Grid-wide barrier: safe because the grid is exactly co-resident
// (1024 blocks at __launch_bounds__(256,4) = 4 blocks/CU x 256 CU, 0 LDS).
__device__ inline void grid_barrier(unsigned* ctr, unsigned target) {
    __syncthreads();
    if (threadIdx.x == 0) {
        __threadfence();                                   // release our writes
        __hip_atomic_fetch_add(ctr, 1u, __ATOMIC_ACQ_REL, __HIP_MEMORY_SCOPE_AGENT);
        while (__hip_atomic_load(ctr, __ATOMIC_ACQUIRE, __HIP_MEMORY_SCOPE_AGENT) < target)
            __builtin_amdgcn_s_sleep(2);
    }
    __syncthreads();
    __threadfence();                                       // acquire for all threads
}

// ---------------------------------------------------------------------------
__global__ __launch_bounds__(256, 4) void mono(const float* __restrict__ Q,
                                               const float* __restrict__ P,
                                               const float* __restrict__ W1,
                                               const float* __restrict__ b1,
                                               const float* __restrict__ W2,
                                               const float* __restrict__ b2,
                                               char* __restrict__ ws,
                                               float* __restrict__ out) {
    unsigned* ctr = (unsigned*)(ws + CTR_BY);
    float* A  = (float*)(ws + A_BY);
    float* Bv = (float*)(ws + B_BY);
    short* PXH = (short*)(ws + PXH_BY);
    short* PWH = (short*)(ws + PWH_BY);
    short* PWL = (short*)(ws + PWL_BY);

    int tid  = threadIdx.x;
    int lane = tid & 63;

    // ---- Phase A: convert/pack into MFMA fragment order -------------------
    {
        int wid = blockIdx.x * 4 + (tid >> 6);      // 0..4095 wave-job id
        int kq  = (lane >> 4) * 8;
        if (wid < XJOBS) {                          // X tiles: hi only
            int rt = wid >> 4, c = wid & 15;
            int r  = rt * 16 + (lane & 15);
            const float* src = (r < NQ ? Q + (size_t)r * EMB
                                       : P + (size_t)(r - NQ) * EMB) + c * 32 + kq;
            float4 v0 = *(const float4*)&src[0];
            float4 v1 = *(const float4*)&src[4];
            short8 hh;
            hh[0] = (short)bfr(v0.x); hh[1] = (short)bfr(v0.y);
            hh[2] = (short)bfr(v0.z); hh[3] = (short)bfr(v0.w);
            hh[4] = (short)bfr(v1.x); hh[5] = (short)bfr(v1.y);
            hh[6] = (short)bfr(v1.z); hh[7] = (short)bfr(v1.w);
            *(short8*)(PXH + (size_t)wid * 512 + lane * 8) = hh;
        } else if (wid < XJOBS + WJOBS) {           // W tiles: hi + lo
            int u = wid - XJOBS;                    // m*128 + half*64 + ht*16 + c
            int c = u & 15, ht = (u >> 4) & 3, half = (u >> 6) & 1, m = u >> 7;
            int h = ht * 16 + (lane & 15);
            const float* src = W1 + ((size_t)m * 64 + h) * 1024 + half * EMB + c * 32 + kq;
            float4 v0 = *(const float4*)&src[0];
            float4 v1 = *(const float4*)&src[4];
            short8 hh, ll;
#define CNV(I, VAL) { unsigned short h_ = bfr(VAL); hh[I] = (short)h_; \
            float hf_ = __uint_as_float(((unsigned)h_) << 16); ll[I] = (short)bfr((VAL) - hf_); }
            CNV(0, v0.x) CNV(1, v0.y) CNV(2, v0.z) CNV(3, v0.w)
            CNV(4, v1.x) CNV(5, v1.y) CNV(6, v1.z) CNV(7, v1.w)
#undef CNV
            *(short8*)(PWH + (size_t)u * 512 + lane * 8) = hh;
            *(short8*)(PWL + (size_t)u * 512 + lane * 8) = ll;
        }
    }
    grid_barrier(ctr, GRID);

    // ---- Phase B: barrier-free packed MFMA GEMM ---------------------------
    if (blockIdx.x < GEMM_BLKS) {
        int ht = tid >> 6;
        int m  = blockIdx.x % 5;
        int rt = blockIdx.x / 5;                    // 0..143
        bool isQ = rt < 128;
        int half = isQ ? 0 : 1;

        const short* ax = PXH + ((size_t)rt * 16) * 512 + lane * 8;
        size_t wbase = ((size_t)((m * 2 + half) * 4 + ht) * 16) * 512 + lane * 8;
        const short* bh = PWH + wbase;
        const short* bl = PWL + wbase;

        floatx4 ac = {0, 0, 0, 0};
#pragma unroll 4
        for (int c = 0; c < NC; ++c) {
            short8 Ah = *(const short8*)&ax[c * 512];
            short8 Bh = *(const short8*)&bh[c * 512];
            short8 Bl = *(const short8*)&bl[c * 512];
            ac = __builtin_amdgcn_mfma_f32_16x16x32_bf16(Ah, Bl, ac, 0, 0, 0);
            ac = __builtin_amdgcn_mfma_f32_16x16x32_bf16(Ah, Bh, ac, 0, 0, 0);
        }

        int col  = lane & 15;
        int rloc = (lane >> 4) * 4;
        int h    = ht * 16 + col;
        int r    = rt * 16 + rloc;
        if (isQ) {
            float bb = b1[m * 64 + h];
            float* dst = &A[((size_t)m * NQ + r) * HID + h];
            dst[0 * HID] = ac.x + bb; dst[1 * HID] = ac.y + bb;
            dst[2 * HID] = ac.z + bb; dst[3 * HID] = ac.w + bb;
        } else {
            int p = r - NQ;
            float* dst = &Bv[(((size_t)(m * 16 + (h >> 2))) * NP + p) * 4 + (h & 3)];
            dst[0 * 4] = ac.x; dst[1 * 4] = ac.y; dst[2 * 4] = ac.z; dst[3 * 4] = ac.w;
        }
    }
    grid_barrier(ctr + 1, GRID);

    // ---- Phase C: fused relu-ensemble + mean/std/exp (4 q / thread) -------
    if (blockIdx.x < FUSED_BLKS) {
        int p  = tid;
        int q0 = blockIdx.x * 4;

        float s10 = 0, s20 = 0, s11 = 0, s21 = 0;
        float s12 = 0, s22 = 0, s13 = 0, s23 = 0;
        const float4* Bq = (const float4*)Bv + p;

#pragma unroll 1
        for (int m = 0; m < NM; ++m) {
            const float4* bm = Bq + (size_t)m * 16 * NP;
            float4 B0 = bm[0*NP],  B1 = bm[1*NP],  B2 = bm[2*NP],  B3 = bm[3*NP];
            float4 B4 = bm[4*NP],  B5 = bm[5*NP],  B6 = bm[6*NP],  B7 = bm[7*NP];
            float4 B8 = bm[8*NP],  B9 = bm[9*NP],  B10= bm[10*NP], B11= bm[11*NP];
            float4 B12= bm[12*NP], B13= bm[13*NP], B14= bm[14*NP], B15= bm[15*NP];

            const float* Ar  = A + ((size_t)m * NQ + q0) * HID;   // block-uniform
            const float* Wp2 = W2 + m * HID;                      // block-uniform
            float o0 = 0.f, o1 = 0.f, o2 = 0.f, o3 = 0.f;

#define HS1(OA, QO, BF, H0, WA, WB, WC, WD) \
            OA = fmaf(fmaxf(Ar[QO*HID+H0+0] + BF.x, 0.f), WA, OA); \
            OA = fmaf(fmaxf(Ar[QO*HID+H0+1] + BF.y, 0.f), WB, OA); \
            OA = fmaf(fmaxf(Ar[QO*HID+H0+2] + BF.z, 0.f), WC, OA); \
            OA = fmaf(fmaxf(Ar[QO*HID+H0+3] + BF.w, 0.f), WD, OA);
#define HSTEP(BF, H0) { \
            float wa=Wp2[H0+0], wb=Wp2[H0+1], wc=Wp2[H0+2], wd=Wp2[H0+3]; \
            HS1(o0, 0, BF, H0, wa, wb, wc, wd) \
            HS1(o1, 1, BF, H0, wa, wb, wc, wd) \
            HS1(o2, 2, BF, H0, wa, wb, wc, wd) \
            HS1(o3, 3, BF, H0, wa, wb, wc, wd) }

            HSTEP(B0,  0)  HSTEP(B1,  4)  HSTEP(B2,  8)  HSTEP(B3, 12)
            HSTEP(B4, 16)  HSTEP(B5, 20)  HSTEP(B6, 24)  HSTEP(B7, 28)
            HSTEP(B8, 32)  HSTEP(B9, 36)  HSTEP(B10,40)  HSTEP(B11,44)
            HSTEP(B12,48)  HSTEP(B13,52)  HSTEP(B14,56)  HSTEP(B15,60)
#undef HSTEP
#undef HS1

            float bb = b2[m];
            float x0 = o0 + bb, x1 = o1 + bb, x2 = o2 + bb, x3 = o3 + bb;
            s10 += x0; s20 = fmaf(x0, x0, s20);
            s11 += x1; s21 = fmaf(x1, x1, s21);
            s12 += x2; s22 = fmaf(x2, x2, s22);
            s13 += x3; s23 = fmaf(x3, x3, s23);
        }

#define OUTW(J, S1, S2) { \
        float mean = S1 * 0.2f; \
        float var  = fmaxf((S2 - S1 * S1 * 0.2f) * 0.25f, 0.f); \
        out[(size_t)(q0 + J) * NP + p] = mean * __expf(-sqrtf(var)); }
        OUTW(0, s10, s20) OUTW(1, s11, s21) OUTW(2, s12, s22) OUTW(3, s13, s23)
#undef OUTW
    }
}

// ---------------------------------------------------------------------------
extern "C" void kernel_launch(void* const* d_in, const int* in_sizes, int n_in,
                              void* d_out, int out_size, void* d_ws, size_t ws_size,
                              hipStream_t stream) {
    const float* Q  = (const float*)d_in[0];   // (2048, 512)
    const float* P  = (const float*)d_in[1];   // (256, 512)
    const float* W1 = (const float*)d_in[2];   // (5, 64, 1024)
    const float* b1 = (const float*)d_in[3];   // (5, 64)
    const float* W2 = (const float*)d_in[4];   // (5, 64)
    const float* b2 = (const float*)d_in[5];   // (5,)
    float* out = (float*)d_out;
    char*  ws  = (char*)d_ws;

    hipMemsetAsync(ws + CTR_BY, 0, 64, stream);   // zero the barrier counters
    mono<<<GRID, 256, 0, stream>>>(Q, P, W1, b1, W2, b2, ws, out);
}

// Round 12
// 111.296 us; speedup vs baseline: 4.0422x; 4.0422x over previous
//
#include <hip/hip_runtime.h>
#include <math.h>

#define EMB 512
#define NM 5
#define HID 64
#define NQ 2048
#define NP 256
#define NC 16                 // K-chunks of 32 (K=512)

typedef __attribute__((ext_vector_type(8))) short short8;   // 8 bf16 = 4 VGPR
typedef __attribute__((ext_vector_type(4))) float floatx4;

// ws layout (bytes)
#define A_BY 0u                    // A[m][q][h] f32 (+b1)   2,621,440
#define B_BY 2621440u              // B[m][h/4][p][h%4] f32    327,680

__device__ inline unsigned short bfr(float f) {            // f32 -> bf16 RNE
    unsigned u = __float_as_uint(f);
    u += 0x7FFFu + ((u >> 16) & 1u);
    return (unsigned short)(u >> 16);
}

// ---------------------------------------------------------------------------
// Kernel 1: direct-convert MFMA GEMM — no LDS, no barriers, no pack pass.
// Grid 720 = (m, rt); block = 4 waves = 4 h-tiles (ht). Each wave loads its
// A fragment (X rows, bf16-hi) and B fragment (W1 rows, hi+lo Ootomo split)
// straight from global (L1/L2-resident), converts in-reg, 2 MFMAs per chunk.
// Verified layouts: A/B frag [row/h = lane&15][k = (lane>>4)*8 + j];
// C/D col=lane&15, row=(lane>>4)*4+reg.
__global__ __launch_bounds__(256) void gemm_direct(const float* __restrict__ Q,
                                                   const float* __restrict__ P,
                                                   const float* __restrict__ W1,
                                                   const float* __restrict__ b1,
                                                   float* __restrict__ A,
                                                   float* __restrict__ Bv) {
    int tid  = threadIdx.x;
    int lane = tid & 63;
    int ht   = tid >> 6;
    int m    = blockIdx.x % 5;
    int rt   = blockIdx.x / 5;           // 0..143
    bool isQ = rt < 128;
    int half = isQ ? 0 : 1;

    int r  = rt * 16 + (lane & 15);
    int kq = (lane >> 4) * 8;
    const float* xsrc = (isQ ? Q + (size_t)r * EMB
                             : P + (size_t)(r - NQ) * EMB) + kq;
    int h = ht * 16 + (lane & 15);
    const float* wsrc = W1 + ((size_t)m * 64 + h) * 1024 + half * EMB + kq;

    floatx4 ac = {0, 0, 0, 0};
#pragma unroll 4
    for (int c = 0; c < NC; ++c) {
        float4 xv0 = *(const float4*)&xsrc[c * 32];
        float4 xv1 = *(const float4*)&xsrc[c * 32 + 4];
        float4 wv0 = *(const float4*)&wsrc[c * 32];
        float4 wv1 = *(const float4*)&wsrc[c * 32 + 4];

        short8 Ah, Bh, Bl;
        Ah[0] = (short)bfr(xv0.x); Ah[1] = (short)bfr(xv0.y);
        Ah[2] = (short)bfr(xv0.z); Ah[3] = (short)bfr(xv0.w);
        Ah[4] = (short)bfr(xv1.x); Ah[5] = (short)bfr(xv1.y);
        Ah[6] = (short)bfr(xv1.z); Ah[7] = (short)bfr(xv1.w);
#define CNV(I, VAL) { unsigned short h_ = bfr(VAL); Bh[I] = (short)h_; \
        float hf_ = __uint_as_float(((unsigned)h_) << 16); Bl[I] = (short)bfr((VAL) - hf_); }
        CNV(0, wv0.x) CNV(1, wv0.y) CNV(2, wv0.z) CNV(3, wv0.w)
        CNV(4, wv1.x) CNV(5, wv1.y) CNV(6, wv1.z) CNV(7, wv1.w)
#undef CNV
        ac = __builtin_amdgcn_mfma_f32_16x16x32_bf16(Ah, Bl, ac, 0, 0, 0);
        ac = __builtin_amdgcn_mfma_f32_16x16x32_bf16(Ah, Bh, ac, 0, 0, 0);
    }

    int col  = lane & 15;                 // h within tile
    int rloc = (lane >> 4) * 4;           // row within tile (+reg)
    int hh   = ht * 16 + col;
    int rr   = rt * 16 + rloc;

    if (isQ) {
        float bb = b1[m * 64 + hh];
        float* dst = &A[((size_t)m * NQ + rr) * HID + hh];
        dst[0 * HID] = ac.x + bb; dst[1 * HID] = ac.y + bb;
        dst[2 * HID] = ac.z + bb; dst[3 * HID] = ac.w + bb;
    } else {
        int p = rr - NQ;
        float* dst = &Bv[(((size_t)(m * 16 + (hh >> 2))) * NP + p) * 4 + (hh & 3)];
        dst[0 * 4] = ac.x; dst[1 * 4] = ac.y; dst[2 * 4] = ac.z; dst[3 * 4] = ac.w;
    }
}

// ---------------------------------------------------------------------------
// Kernel 2: fused relu-ensemble + mean/std/exp. 4 q per thread (512 blocks).
__global__ __launch_bounds__(256) void fused_main(const float* __restrict__ A,
                                                  const float* __restrict__ Bv,
                                                  const float* __restrict__ W2,
                                                  const float* __restrict__ b2,
                                                  float* __restrict__ out) {
    int p  = threadIdx.x;            // 0..255
    int q0 = blockIdx.x * 4;

    float s10 = 0, s20 = 0, s11 = 0, s21 = 0;
    float s12 = 0, s22 = 0, s13 = 0, s23 = 0;
    const float4* Bq = (const float4*)Bv + p;

#pragma unroll 1
    for (int m = 0; m < NM; ++m) {
        const float4* bm = Bq + (size_t)m * 16 * NP;
        float4 B0 = bm[0*NP],  B1 = bm[1*NP],  B2 = bm[2*NP],  B3 = bm[3*NP];
        float4 B4 = bm[4*NP],  B5 = bm[5*NP],  B6 = bm[6*NP],  B7 = bm[7*NP];
        float4 B8 = bm[8*NP],  B9 = bm[9*NP],  B10= bm[10*NP], B11= bm[11*NP];
        float4 B12= bm[12*NP], B13= bm[13*NP], B14= bm[14*NP], B15= bm[15*NP];

        const float* Ar  = A + ((size_t)m * NQ + q0) * HID;   // block-uniform
        const float* Wp2 = W2 + m * HID;                      // block-uniform
        float o0 = 0.f, o1 = 0.f, o2 = 0.f, o3 = 0.f;

#define HS1(OA, QO, BF, H0, WA, WB, WC, WD) \
        OA = fmaf(fmaxf(Ar[QO*HID+H0+0] + BF.x, 0.f), WA, OA); \
        OA = fmaf(fmaxf(Ar[QO*HID+H0+1] + BF.y, 0.f), WB, OA); \
        OA = fmaf(fmaxf(Ar[QO*HID+H0+2] + BF.z, 0.f), WC, OA); \
        OA = fmaf(fmaxf(Ar[QO*HID+H0+3] + BF.w, 0.f), WD, OA);
#define HSTEP(BF, H0) { \
        float wa=Wp2[H0+0], wb=Wp2[H0+1], wc=Wp2[H0+2], wd=Wp2[H0+3]; \
        HS1(o0, 0, BF, H0, wa, wb, wc, wd) \
        HS1(o1, 1, BF, H0, wa, wb, wc, wd) \
        HS1(o2, 2, BF, H0, wa, wb, wc, wd) \
        HS1(o3, 3, BF, H0, wa, wb, wc, wd) }

        HSTEP(B0,  0)  HSTEP(B1,  4)  HSTEP(B2,  8)  HSTEP(B3, 12)
        HSTEP(B4, 16)  HSTEP(B5, 20)  HSTEP(B6, 24)  HSTEP(B7, 28)
        HSTEP(B8, 32)  HSTEP(B9, 36)  HSTEP(B10,40)  HSTEP(B11,44)
        HSTEP(B12,48)  HSTEP(B13,52)  HSTEP(B14,56)  HSTEP(B15,60)
#undef HSTEP
#undef HS1

        float bb = b2[m];
        float x0 = o0 + bb, x1 = o1 + bb, x2 = o2 + bb, x3 = o3 + bb;
        s10 += x0; s20 = fmaf(x0, x0, s20);
        s11 += x1; s21 = fmaf(x1, x1, s21);
        s12 += x2; s22 = fmaf(x2, x2, s22);
        s13 += x3; s23 = fmaf(x3, x3, s23);
    }

#define OUTW(J, S1, S2) { \
        float mean = S1 * 0.2f; \
        float var  = fmaxf((S2 - S1 * S1 * 0.2f) * 0.25f, 0.f); \
        out[(size_t)(q0 + J) * NP + p] = mean * __expf(-sqrtf(var)); }
    OUTW(0, s10, s20) OUTW(1, s11, s21) OUTW(2, s12, s22) OUTW(3, s13, s23)
#undef OUTW
}

// ---------------------------------------------------------------------------
extern "C" void kernel_launch(void* const* d_in, const int* in_sizes, int n_in,
                              void* d_out, int out_size, void* d_ws, size_t ws_size,
                              hipStream_t stream) {
    const float* Q  = (const float*)d_in[0];   // (2048, 512)
    const float* P  = (const float*)d_in[1];   // (256, 512)
    const float* W1 = (const float*)d_in[2];   // (5, 64, 1024)
    const float* b1 = (const float*)d_in[3];   // (5, 64)
    const float* W2 = (const float*)d_in[4];   // (5, 64)
    const float* b2 = (const float*)d_in[5];   // (5,)
    float* out = (float*)d_out;

    char*  ws = (char*)d_ws;
    float* A  = (float*)(ws + A_BY);
    float* B  = (float*)(ws + B_BY);

    gemm_direct<<<720, 256, 0, stream>>>(Q, P, W1, b1, A, B);
    fused_main<<<NQ / 4, 256, 0, stream>>>(A, B, W2, b2, out);
}

// Round 13
// 94.136 us; speedup vs baseline: 4.7791x; 1.1823x over previous
//
#include <hip/hip_runtime.h>
#include <math.h>

#define EMB 512
#define NM 5
#define HID 64
#define NQ 2048
#define NP 256

typedef __attribute__((ext_vector_type(8))) short short8;   // 8 bf16 = 4 VGPR
typedef __attribute__((ext_vector_type(4))) short short4v;  // 4 bf16 = 8B
typedef __attribute__((ext_vector_type(4))) float floatx4;

// ws layout (bytes)
#define A_BY 0u                    // A[m][q][h] f32 (+b1)   2,621,440
#define B_BY 2621440u              // B[m][h/4][p][h%4] f32    327,680

#define LST 72                     // LDS row stride in shorts (144B): reads hit
                                   // the 8-phase floor, b64 writes the 4-phase floor

__device__ inline unsigned short bfr(float f) {            // f32 -> bf16 RNE
    unsigned u = __float_as_uint(f);
    u += 0x7FFFu + ((u >> 16) & 1u);
    return (unsigned short)(u >> 16);
}

// ---------------------------------------------------------------------------
// Kernel 1: LDS-staged MFMA GEMM, grid 720 (= 5 m x 144 row-tiles of 16).
// Block = 4 waves = 4 h-tiles of 16. K=512 in 8 chunks of 64. X staged once
// (bf16-hi), shared by all 4 waves; W staged hi+lo (2-term Ootomo split:
// Ah*Bl + Ah*Bh, measured absmax 9.8e-4). All global loads coalesced.
__global__ __launch_bounds__(256) void gemm_v2(const float* __restrict__ Q,
                                               const float* __restrict__ P,
                                               const float* __restrict__ W1,
                                               const float* __restrict__ b1,
                                               float* __restrict__ A,
                                               float* __restrict__ Bv) {
    __shared__ short XH[16 * LST];
    __shared__ short WH[64 * LST];
    __shared__ short WL[64 * LST];

    int tid  = threadIdx.x;
    int lane = tid & 63;
    int ht   = tid >> 6;
    int m    = blockIdx.x % 5;
    int rt   = blockIdx.x / 5;           // 0..143
    int r0   = rt * 16;
    bool isQ = rt < 128;

    // staging coords: 16 lanes cover one row's 64B run -> coalesced
    int xrow = tid >> 4;                 // 0..15
    int xk   = (tid & 15) * 4;           // element offset 0..60
    const float* xbase = (isQ ? Q + (size_t)(r0 + xrow) * EMB
                              : P + (size_t)(r0 - NQ + xrow) * EMB) + xk;
    const float* wb = W1 + (size_t)m * 64 * 1024 + (isQ ? 0 : EMB) + xk;
    int wr0 = tid >> 4;                  // W rows wr0 + 16*i

    // compute-side LDS offsets (shorts)
    int arix = (lane & 15) * LST + (lane >> 4) * 8;
    int brix = (ht * 16 + (lane & 15)) * LST + (lane >> 4) * 8;

    floatx4 ac = {0, 0, 0, 0};

#pragma unroll 1
    for (int c = 0; c < 8; ++c) {
        int k0 = c * 64;
        float4 xv  = *(const float4*)&xbase[k0];
        float4 wv0 = *(const float4*)&wb[(size_t)(wr0 +  0) * 1024 + k0];
        float4 wv1 = *(const float4*)&wb[(size_t)(wr0 + 16) * 1024 + k0];
        float4 wv2 = *(const float4*)&wb[(size_t)(wr0 + 32) * 1024 + k0];
        float4 wv3 = *(const float4*)&wb[(size_t)(wr0 + 48) * 1024 + k0];

        __syncthreads();                 // previous chunk's fragment reads done

        {   // X: hi only
            short4v xs;
            xs[0] = (short)bfr(xv.x); xs[1] = (short)bfr(xv.y);
            xs[2] = (short)bfr(xv.z); xs[3] = (short)bfr(xv.w);
            *(short4v*)&XH[xrow * LST + xk] = xs;
        }
#define WSTG(WV, I) { short4v hi, lo; \
        { unsigned short h_ = bfr(WV.x); hi[0] = (short)h_; \
          lo[0] = (short)bfr(WV.x - __uint_as_float(((unsigned)h_) << 16)); } \
        { unsigned short h_ = bfr(WV.y); hi[1] = (short)h_; \
          lo[1] = (short)bfr(WV.y - __uint_as_float(((unsigned)h_) << 16)); } \
        { unsigned short h_ = bfr(WV.z); hi[2] = (short)h_; \
          lo[2] = (short)bfr(WV.z - __uint_as_float(((unsigned)h_) << 16)); } \
        { unsigned short h_ = bfr(WV.w); hi[3] = (short)h_; \
          lo[3] = (short)bfr(WV.w - __uint_as_float(((unsigned)h_) << 16)); } \
        *(short4v*)&WH[(wr0 + 16 * I) * LST + xk] = hi; \
        *(short4v*)&WL[(wr0 + 16 * I) * LST + xk] = lo; }
        WSTG(wv0, 0) WSTG(wv1, 1) WSTG(wv2, 2) WSTG(wv3, 3)
#undef WSTG
        __syncthreads();

#pragma unroll
        for (int s = 0; s < 2; ++s) {    // two 32-k sub-chunks
            short8 Ah = *(const short8*)&XH[arix + s * 32];
            short8 Bh = *(const short8*)&WH[brix + s * 32];
            short8 Bl = *(const short8*)&WL[brix + s * 32];
            ac = __builtin_amdgcn_mfma_f32_16x16x32_bf16(Ah, Bl, ac, 0, 0, 0);
            ac = __builtin_amdgcn_mfma_f32_16x16x32_bf16(Ah, Bh, ac, 0, 0, 0);
        }
    }

    int col  = lane & 15;                 // h within tile
    int rloc = (lane >> 4) * 4;           // row within tile (+reg)
    int hh   = ht * 16 + col;
    int rr   = r0 + rloc;

    if (isQ) {
        float bb = b1[m * 64 + hh];
        float* dst = &A[((size_t)m * NQ + rr) * HID + hh];
        dst[0 * HID] = ac.x + bb; dst[1 * HID] = ac.y + bb;
        dst[2 * HID] = ac.z + bb; dst[3 * HID] = ac.w + bb;
    } else {
        int p = rr - NQ;
        float* dst = &Bv[(((size_t)(m * 16 + (hh >> 2))) * NP + p) * 4 + (hh & 3)];
        dst[0 * 4] = ac.x; dst[1 * 4] = ac.y; dst[2 * 4] = ac.z; dst[3 * 4] = ac.w;
    }
}

// ---------------------------------------------------------------------------
// Kernel 2: fused relu-ensemble + mean/std/exp — R8's exact 2q/thread kernel
// (1024 blocks = 4 blocks/CU; best measured configuration).
__global__ __launch_bounds__(256) void fused_main(const float* __restrict__ A,
                                                  const float* __restrict__ Bv,
                                                  const float* __restrict__ W2,
                                                  const float* __restrict__ b2,
                                                  float* __restrict__ out) {
    int p  = threadIdx.x;            // 0..255
    int q0 = blockIdx.x * 2;

    float s1a = 0, s2a = 0, s1b = 0, s2b = 0;
    const float4* Bq = (const float4*)Bv + p;

#pragma unroll 1
    for (int m = 0; m < NM; ++m) {
        const float4* bm = Bq + (size_t)m * 16 * NP;
        float4 B0 = bm[0*NP],  B1 = bm[1*NP],  B2 = bm[2*NP],  B3 = bm[3*NP];
        float4 B4 = bm[4*NP],  B5 = bm[5*NP],  B6 = bm[6*NP],  B7 = bm[7*NP];
        float4 B8 = bm[8*NP],  B9 = bm[9*NP],  B10= bm[10*NP], B11= bm[11*NP];
        float4 B12= bm[12*NP], B13= bm[13*NP], B14= bm[14*NP], B15= bm[15*NP];

        const float* Ar  = A + ((size_t)m * NQ + q0) * HID;   // block-uniform
        const float* Wp2 = W2 + m * HID;                      // block-uniform
        float oa = 0.f, ob = 0.f;

#define HSTEP(BF, H0) { \
        float wa=Wp2[H0+0], wb=Wp2[H0+1], wc=Wp2[H0+2], wd=Wp2[H0+3]; \
        oa = fmaf(fmaxf(Ar[H0+0]    + BF.x, 0.f), wa, oa); \
        oa = fmaf(fmaxf(Ar[H0+1]    + BF.y, 0.f), wb, oa); \
        oa = fmaf(fmaxf(Ar[H0+2]    + BF.z, 0.f), wc, oa); \
        oa = fmaf(fmaxf(Ar[H0+3]    + BF.w, 0.f), wd, oa); \
        ob = fmaf(fmaxf(Ar[64+H0+0] + BF.x, 0.f), wa, ob); \
        ob = fmaf(fmaxf(Ar[64+H0+1] + BF.y, 0.f), wb, ob); \
        ob = fmaf(fmaxf(Ar[64+H0+2] + BF.z, 0.f), wc, ob); \
        ob = fmaf(fmaxf(Ar[64+H0+3] + BF.w, 0.f), wd, ob); }

        HSTEP(B0,  0)  HSTEP(B1,  4)  HSTEP(B2,  8)  HSTEP(B3, 12)
        HSTEP(B4, 16)  HSTEP(B5, 20)  HSTEP(B6, 24)  HSTEP(B7, 28)
        HSTEP(B8, 32)  HSTEP(B9, 36)  HSTEP(B10,40)  HSTEP(B11,44)
        HSTEP(B12,48)  HSTEP(B13,52)  HSTEP(B14,56)  HSTEP(B15,60)
#undef HSTEP

        float bb = b2[m];
        float xa = oa + bb, xb = ob + bb;
        s1a += xa; s2a = fmaf(xa, xa, s2a);
        s1b += xb; s2b = fmaf(xb, xb, s2b);
    }

    {
        float mean = s1a * 0.2f;
        float var  = fmaxf((s2a - s1a * s1a * 0.2f) * 0.25f, 0.f);
        out[(size_t)q0 * NP + p] = mean * __expf(-sqrtf(var));
    }
    {
        float mean = s1b * 0.2f;
        float var  = fmaxf((s2b - s1b * s1b * 0.2f) * 0.25f, 0.f);
        out[(size_t)(q0 + 1) * NP + p] = mean * __expf(-sqrtf(var));
    }
}

// ---------------------------------------------------------------------------
extern "C" void kernel_launch(void* const* d_in, const int* in_sizes, int n_in,
                              void* d_out, int out_size, void* d_ws, size_t ws_size,
                              hipStream_t stream) {
    const float* Q  = (const float*)d_in[0];   // (2048, 512)
    const float* P  = (const float*)d_in[1];   // (256, 512)
    const float* W1 = (const float*)d_in[2];   // (5, 64, 1024)
    const float* b1 = (const float*)d_in[3];   // (5, 64)
    const float* W2 = (const float*)d_in[4];   // (5, 64)
    const float* b2 = (const float*)d_in[5];   // (5,)
    float* out = (float*)d_out;

    char*  ws = (char*)d_ws;
    float* A  = (float*)(ws + A_BY);
    float* B  = (float*)(ws + B_BY);

    gemm_v2<<<720, 256, 0, stream>>>(Q, P, W1, b1, A, B);
    fused_main<<<1024, 256, 0, stream>>>(A, B, W2, b2, out);
}

// Round 14
// 92.618 us; speedup vs baseline: 4.8574x; 1.0164x over previous
//
#include <hip/hip_runtime.h>
#include <math.h>

#define EMB 512
#define NM 5
#define HID 64
#define NQ 2048
#define NP 256

typedef __attribute__((ext_vector_type(8))) short short8;   // 8 bf16 = 16B
typedef __attribute__((ext_vector_type(4))) float floatx4;

// ws layout (bytes)
#define A_BY 0u                    // A[m][q][h] f32 (+b1)   2,621,440
#define B_BY 2621440u              // B[m][h/4][p][h%4] f32    327,680

#define LST 72                     // LDS row stride in shorts (144B, 16B-aligned)

__device__ inline unsigned short bfr(float f) {            // f32 -> bf16 RNE
    unsigned u = __float_as_uint(f);
    u += 0x7FFFu + ((u >> 16) & 1u);
    return (unsigned short)(u >> 16);
}

__device__ inline void cvt8(float4 a, float4 b, short8& hi, short8& lo) {
#define C1(I, V) { unsigned short h_ = bfr(V); hi[I] = (short)h_; \
    lo[I] = (short)bfr(V - __uint_as_float(((unsigned)h_) << 16)); }
    C1(0, a.x) C1(1, a.y) C1(2, a.z) C1(3, a.w)
    C1(4, b.x) C1(5, b.y) C1(6, b.z) C1(7, b.w)
#undef C1
}
__device__ inline void cvt8hi(float4 a, float4 b, short8& hi) {
    hi[0] = (short)bfr(a.x); hi[1] = (short)bfr(a.y);
    hi[2] = (short)bfr(a.z); hi[3] = (short)bfr(a.w);
    hi[4] = (short)bfr(b.x); hi[5] = (short)bfr(b.y);
    hi[6] = (short)bfr(b.z); hi[7] = (short)bfr(b.w);
}

// ---------------------------------------------------------------------------
// Kernel 1: LDS double-buffered MFMA GEMM — ONE barrier per 64-K chunk.
// Grid 720 = (m, rt of 16 rows); block = 4 waves = 4 h-tiles of 16.
// Staging: thread converts 8 consecutive k of one row -> b128 LDS writes
// (W: 2 rows hi+lo = 4x b128; X: tid<128 only, 1x b128, hi-only 2-term
// Ootomo: Ah*Bl + Ah*Bh, measured absmax 9.8e-4). Loads for chunk c+1 are
// issued before the barrier+MFMA of chunk c, so the vmcnt wait is covered.
__global__ __launch_bounds__(256) void gemm_v3(const float* __restrict__ Q,
                                               const float* __restrict__ P,
                                               const float* __restrict__ W1,
                                               const float* __restrict__ b1,
                                               float* __restrict__ A,
                                               float* __restrict__ Bv) {
    __shared__ short XH[2][16 * LST];
    __shared__ short WH[2][64 * LST];
    __shared__ short WL[2][64 * LST];

    int tid  = threadIdx.x;
    int lane = tid & 63;
    int ht   = tid >> 6;
    int m    = blockIdx.x % 5;
    int rt   = blockIdx.x / 5;           // 0..143
    int r0   = rt * 16;
    bool isQ = rt < 128;

    // staging coords: thread -> (row pair, k-group of 8 floats)
    int wrow = tid >> 3;                 // 0..31  (also rows +32)
    int wg8  = (tid & 7) * 8;            // k offset within 64-chunk
    const float* wb  = W1 + (size_t)m * 64 * 1024 + (isQ ? 0 : EMB);
    const float* wp0 = wb + (size_t)wrow * 1024 + wg8;
    const float* wp1 = wb + (size_t)(wrow + 32) * 1024 + wg8;
    bool hasX = tid < 128;
    int xrow  = tid >> 3;                // 0..15 when hasX
    const float* xp = (isQ ? Q + (size_t)(r0 + xrow) * EMB
                           : P + (size_t)(r0 - NQ + xrow) * EMB) + wg8;

    // compute-side LDS offsets (shorts)
    int arix = (lane & 15) * LST + (lane >> 4) * 8;
    int brix = (ht * 16 + (lane & 15)) * LST + (lane >> 4) * 8;

    floatx4 ac = {0, 0, 0, 0};
    float4 w00, w01, w10, w11, x0, x1;

    // prologue: load + convert + store chunk 0 into buf 0
    w00 = *(const float4*)&wp0[0]; w01 = *(const float4*)&wp0[4];
    w10 = *(const float4*)&wp1[0]; w11 = *(const float4*)&wp1[4];
    if (hasX) { x0 = *(const float4*)&xp[0]; x1 = *(const float4*)&xp[4]; }
    {
        short8 hi, lo;
        cvt8(w00, w01, hi, lo);
        *(short8*)&WH[0][wrow * LST + wg8] = hi;
        *(short8*)&WL[0][wrow * LST + wg8] = lo;
        cvt8(w10, w11, hi, lo);
        *(short8*)&WH[0][(wrow + 32) * LST + wg8] = hi;
        *(short8*)&WL[0][(wrow + 32) * LST + wg8] = lo;
        if (hasX) { short8 xh; cvt8hi(x0, x1, xh);
                    *(short8*)&XH[0][xrow * LST + wg8] = xh; }
    }

#pragma unroll 1
    for (int c = 0; c < 8; ++c) {
        int cur = c & 1;
        if (c < 7) {                      // issue loads for c+1 (no wait)
            int k0 = (c + 1) * 64;
            w00 = *(const float4*)&wp0[k0]; w01 = *(const float4*)&wp0[k0 + 4];
            w10 = *(const float4*)&wp1[k0]; w11 = *(const float4*)&wp1[k0 + 4];
            if (hasX) { x0 = *(const float4*)&xp[k0]; x1 = *(const float4*)&xp[k0 + 4]; }
        }
        __syncthreads();                  // buf[cur] writes done; buf[cur^1] readers done

#pragma unroll
        for (int s = 0; s < 2; ++s) {     // two 32-k sub-chunks
            short8 Ah = *(const short8*)&XH[cur][arix + s * 32];
            short8 Bh = *(const short8*)&WH[cur][brix + s * 32];
            short8 Bl = *(const short8*)&WL[cur][brix + s * 32];
            ac = __builtin_amdgcn_mfma_f32_16x16x32_bf16(Ah, Bl, ac, 0, 0, 0);
            ac = __builtin_amdgcn_mfma_f32_16x16x32_bf16(Ah, Bh, ac, 0, 0, 0);
        }

        if (c < 7) {                      // convert (vmcnt wait lands here) + store
            int nb = cur ^ 1;
            short8 hi, lo;
            cvt8(w00, w01, hi, lo);
            *(short8*)&WH[nb][wrow * LST + wg8] = hi;
            *(short8*)&WL[nb][wrow * LST + wg8] = lo;
            cvt8(w10, w11, hi, lo);
            *(short8*)&WH[nb][(wrow + 32) * LST + wg8] = hi;
            *(short8*)&WL[nb][(wrow + 32) * LST + wg8] = lo;
            if (hasX) { short8 xh; cvt8hi(x0, x1, xh);
                        *(short8*)&XH[nb][xrow * LST + wg8] = xh; }
        }
    }

    int col  = lane & 15;                 // h within tile
    int rloc = (lane >> 4) * 4;           // row within tile (+reg)
    int hh   = ht * 16 + col;
    int rr   = r0 + rloc;

    if (isQ) {
        float bb = b1[m * 64 + hh];
        float* dst = &A[((size_t)m * NQ + rr) * HID + hh];
        dst[0 * HID] = ac.x + bb; dst[1 * HID] = ac.y + bb;
        dst[2 * HID] = ac.z + bb; dst[3 * HID] = ac.w + bb;
    } else {
        int p = rr - NQ;
        float* dst = &Bv[(((size_t)(m * 16 + (hh >> 2))) * NP + p) * 4 + (hh & 3)];
        dst[0 * 4] = ac.x; dst[1 * 4] = ac.y; dst[2 * 4] = ac.z; dst[3 * 4] = ac.w;
    }
}

// ---------------------------------------------------------------------------
// Kernel 2: fused relu-ensemble + mean/std/exp — 2q/thread, 1024 blocks
// (best measured configuration; unchanged from R13).
__global__ __launch_bounds__(256) void fused_main(const float* __restrict__ A,
                                                  const float* __restrict__ Bv,
                                                  const float* __restrict__ W2,
                                                  const float* __restrict__ b2,
                                                  float* __restrict__ out) {
    int p  = threadIdx.x;            // 0..255
    int q0 = blockIdx.x * 2;

    float s1a = 0, s2a = 0, s1b = 0, s2b = 0;
    const float4* Bq = (const float4*)Bv + p;

#pragma unroll 1
    for (int m = 0; m < NM; ++m) {
        const float4* bm = Bq + (size_t)m * 16 * NP;
        float4 B0 = bm[0*NP],  B1 = bm[1*NP],  B2 = bm[2*NP],  B3 = bm[3*NP];
        float4 B4 = bm[4*NP],  B5 = bm[5*NP],  B6 = bm[6*NP],  B7 = bm[7*NP];
        float4 B8 = bm[8*NP],  B9 = bm[9*NP],  B10= bm[10*NP], B11= bm[11*NP];
        float4 B12= bm[12*NP], B13= bm[13*NP], B14= bm[14*NP], B15= bm[15*NP];

        const float* Ar  = A + ((size_t)m * NQ + q0) * HID;   // block-uniform
        const float* Wp2 = W2 + m * HID;                      // block-uniform
        float oa = 0.f, ob = 0.f;

#define HSTEP(BF, H0) { \
        float wa=Wp2[H0+0], wb=Wp2[H0+1], wc=Wp2[H0+2], wd=Wp2[H0+3]; \
        oa = fmaf(fmaxf(Ar[H0+0]    + BF.x, 0.f), wa, oa); \
        oa = fmaf(fmaxf(Ar[H0+1]    + BF.y, 0.f), wb, oa); \
        oa = fmaf(fmaxf(Ar[H0+2]    + BF.z, 0.f), wc, oa); \
        oa = fmaf(fmaxf(Ar[H0+3]    + BF.w, 0.f), wd, oa); \
        ob = fmaf(fmaxf(Ar[64+H0+0] + BF.x, 0.f), wa, ob); \
        ob = fmaf(fmaxf(Ar[64+H0+1] + BF.y, 0.f), wb, ob); \
        ob = fmaf(fmaxf(Ar[64+H0+2] + BF.z, 0.f), wc, ob); \
        ob = fmaf(fmaxf(Ar[64+H0+3] + BF.w, 0.f), wd, ob); }

        HSTEP(B0,  0)  HSTEP(B1,  4)  HSTEP(B2,  8)  HSTEP(B3, 12)
        HSTEP(B4, 16)  HSTEP(B5, 20)  HSTEP(B6, 24)  HSTEP(B7, 28)
        HSTEP(B8, 32)  HSTEP(B9, 36)  HSTEP(B10,40)  HSTEP(B11,44)
        HSTEP(B12,48)  HSTEP(B13,52)  HSTEP(B14,56)  HSTEP(B15,60)
#undef HSTEP

        float bb = b2[m];
        float xa = oa + bb, xb = ob + bb;
        s1a += xa; s2a = fmaf(xa, xa, s2a);
        s1b += xb; s2b = fmaf(xb, xb, s2b);
    }

    {
        float mean = s1a * 0.2f;
        float var  = fmaxf((s2a - s1a * s1a * 0.2f) * 0.25f, 0.f);
        out[(size_t)q0 * NP + p] = mean * __expf(-sqrtf(var));
    }
    {
        float mean = s1b * 0.2f;
        float var  = fmaxf((s2b - s1b * s1b * 0.2f) * 0.25f, 0.f);
        out[(size_t)(q0 + 1) * NP + p] = mean * __expf(-sqrtf(var));
    }
}

// ---------------------------------------------------------------------------
extern "C" void kernel_launch(void* const* d_in, const int* in_sizes, int n_in,
                              void* d_out, int out_size, void* d_ws, size_t ws_size,
                              hipStream_t stream) {
    const float* Q  = (const float*)d_in[0];   // (2048, 512)
    const float* P  = (const float*)d_in[1];   // (256, 512)
    const float* W1 = (const float*)d_in[2];   // (5, 64, 1024)
    const float* b1 = (const float*)d_in[3];   // (5, 64)
    const float* W2 = (const float*)d_in[4];   // (5, 64)
    const float* b2 = (const float*)d_in[5];   // (5,)
    float* out = (float*)d_out;

    char*  ws = (char*)d_ws;
    float* A  = (float*)(ws + A_BY);
    float* B  = (float*)(ws + B_BY);

    gemm_v3<<<720, 256, 0, stream>>>(Q, P, W1, b1, A, B);
    fused_main<<<1024, 256, 0, stream>>>(A, B, W2, b2, out);
}